// Round 1
// baseline (862.642 us; speedup 1.0000x reference)
//
#include <hip/hip_runtime.h>

#define B_ 512
#define H_ 512

typedef __attribute__((ext_vector_type(8))) short short8;
typedef __attribute__((ext_vector_type(4))) float f32x4;

__device__ __forceinline__ unsigned short bf16hi(float f) {
  unsigned u = __float_as_uint(f);
  u += 0x7FFFu + ((u >> 16) & 1u);
  return (unsigned short)(u >> 16);
}
__device__ __forceinline__ float bf16f(unsigned short h) {
  return __uint_as_float(((unsigned)h) << 16);
}

// hx[j][h] = sum_n x[j][n]*W1[h][n] + b1[h]   (b1 folded into hx)
// hy[i][h] = sum_n y[i][n]*W1[h][128+n]
__global__ __launch_bounds__(256) void k_prep(const float* __restrict__ x,
                                              const float* __restrict__ y,
                                              const float* __restrict__ W1,
                                              const float* __restrict__ b1,
                                              float* __restrict__ hx,
                                              float* __restrict__ hy) {
  __shared__ float xs[128];
  const int b = blockIdx.x;          // 0..1023
  const bool isx = b < B_;
  const int row = isx ? b : b - B_;
  const float* src = (isx ? x : y) + row * 128;
  const int t = threadIdx.x;
  if (t < 32) ((float4*)xs)[t] = ((const float4*)src)[t];
  __syncthreads();
  const int woff = isx ? 0 : 128;
  float* dst = (isx ? hx : hy) + row * H_;
  for (int h = t; h < H_; h += 256) {
    const float4* wr = (const float4*)(W1 + h * 256 + woff);
    float acc = isx ? b1[h] : 0.f;
#pragma unroll
    for (int n = 0; n < 32; ++n) {
      float4 w = wr[n];
      float4 xv = ((const float4*)xs)[n];
      acc = fmaf(w.x, xv.x, acc);
      acc = fmaf(w.y, xv.y, acc);
      acc = fmaf(w.z, xv.z, acc);
      acc = fmaf(w.w, xv.w, acc);
    }
    dst[h] = acc;
  }
}

// split W2 (fp32) into bf16 hi/lo planes
__global__ __launch_bounds__(256) void k_split(const float* __restrict__ W2,
                                               unsigned short* __restrict__ hi,
                                               unsigned short* __restrict__ lo) {
  int e = blockIdx.x * 256 + threadIdx.x;  // grid 1024 -> 262144
  float v = W2[e];
  unsigned short h = bf16hi(v);
  hi[e] = h;
  lo[e] = bf16hi(v - bf16f(h));
}

// Fused: score[i,j] = sum_g w3[g]*relu( sum_h relu(hx[j,h]+hy[i,h]) * W2[g,h] + b2[g] ) + b3
// Block: pair-tile 256 (16 i x 16 j) x g-tile 128. 8 waves = 4(M) x 2(N), wave tile 64x64.
// K chunked by 32, h1 built into LDS (bf16 hi/lo, XOR-swizzled), double-buffered.
__global__ __launch_bounds__(512, 2) void k_main(
    const float* __restrict__ hx, const float* __restrict__ hy,
    const unsigned short* __restrict__ w2hi, const unsigned short* __restrict__ w2lo,
    const float* __restrict__ b2, const float* __restrict__ w3,
    const float* __restrict__ b3, float* __restrict__ out) {
  __shared__ alignas(16) unsigned short Ah[2][256 * 32];  // 16 KB per buf
  __shared__ alignas(16) unsigned short Al[2][256 * 32];  // total 64 KB

  const int tid = threadIdx.x;
  const int lane = tid & 63;
  const int wid = tid >> 6;   // 0..7
  const int wm = wid >> 1;    // 0..3 (M group)
  const int wn = wid & 1;     // 0..1 (N group)

  const int bid = blockIdx.x;
  const int ntile = bid & 3;
  const int mtile = bid >> 2;
  const int ibase = (mtile >> 5) << 4;
  const int jbase = (mtile & 31) << 4;
  const int gbase = ntile << 7;

  // ---- A-build statics: thread t handles row = t>>1 (16 consecutive k) ----
  const int brow = tid >> 1;             // 0..255 = i_l*16 + j_l
  const int bi = brow >> 4, bj = brow & 15;
  const int bks = (tid & 1) << 4;        // k offset within chunk: 0 or 16
  const float* hxrow = hx + (jbase + bj) * H_;
  const float* hyrow = hy + (ibase + bi) * H_;
  const unsigned bswz = (((unsigned)brow >> 1) & 3u) << 4;
  const unsigned wo0 = (unsigned)brow * 64u + (((unsigned)(bks * 2)) ^ bswz);
  const unsigned wo1 = (unsigned)brow * 64u + (((unsigned)(bks * 2 + 16)) ^ bswz);

  // ---- A-frag read offsets (16x16x32: A row = lane&15, k = 8*(lane>>4)+e) ----
  const int arl = lane & 15;
  const unsigned akb = ((unsigned)(lane >> 4)) << 4;  // 0,16,32,48 bytes
  unsigned aoff[4];
#pragma unroll
  for (int mf = 0; mf < 4; ++mf) {
    int row = wm * 64 + mf * 16 + arl;
    aoff[mf] = (unsigned)row * 64u + (akb ^ ((((unsigned)row >> 1) & 3u) << 4));
  }

  // ---- B-frag: B[k][n]=W2[g][h]; lane: g = gbase+wn*64+nf*16+(lane&15), k contiguous ----
  const int bg0 = gbase + wn * 64 + arl;
  const int bko = (lane >> 4) << 3;

  f32x4 acc[4][4] = {};

  auto build = [&](int c, int nb) {
    const int k0 = c * 32 + bks;
    const float* hxp = hxrow + k0;
    const float* hyp = hyrow + k0;
    float va[16];
#pragma unroll
    for (int q4 = 0; q4 < 4; ++q4) {
      float4 xv = *(const float4*)(hxp + q4 * 4);
      float4 yv = *(const float4*)(hyp + q4 * 4);
      va[q4 * 4 + 0] = fmaxf(xv.x + yv.x, 0.f);
      va[q4 * 4 + 1] = fmaxf(xv.y + yv.y, 0.f);
      va[q4 * 4 + 2] = fmaxf(xv.z + yv.z, 0.f);
      va[q4 * 4 + 3] = fmaxf(xv.w + yv.w, 0.f);
    }
    short8 Hv0, Hv1, Lv0, Lv1;
#pragma unroll
    for (int q = 0; q < 8; ++q) {
      unsigned short h0 = bf16hi(va[q]);
      unsigned short h1 = bf16hi(va[q + 8]);
      Hv0[q] = (short)h0;
      Hv1[q] = (short)h1;
      Lv0[q] = (short)bf16hi(va[q] - bf16f(h0));
      Lv1[q] = (short)bf16hi(va[q + 8] - bf16f(h1));
    }
    *(short8*)((char*)Ah[nb] + wo0) = Hv0;
    *(short8*)((char*)Ah[nb] + wo1) = Hv1;
    *(short8*)((char*)Al[nb] + wo0) = Lv0;
    *(short8*)((char*)Al[nb] + wo1) = Lv1;
  };

  build(0, 0);
  __syncthreads();

  for (int c = 0; c < 16; ++c) {
    const int buf = c & 1;
    // B loads first (L2, ~200cy) — latency covered by the build below
    short8 Bh[4], Bl[4];
#pragma unroll
    for (int nf = 0; nf < 4; ++nf) {
      const unsigned short* ph = w2hi + (bg0 + nf * 16) * H_ + c * 32 + bko;
      const unsigned short* pl = w2lo + (bg0 + nf * 16) * H_ + c * 32 + bko;
      Bh[nf] = *(const short8*)ph;
      Bl[nf] = *(const short8*)pl;
    }
    if (c < 15) build(c + 1, buf ^ 1);
    short8 Ahf[4], Alf[4];
#pragma unroll
    for (int mf = 0; mf < 4; ++mf) {
      Ahf[mf] = *(const short8*)((const char*)Ah[buf] + aoff[mf]);
      Alf[mf] = *(const short8*)((const char*)Al[buf] + aoff[mf]);
    }
#pragma unroll
    for (int mf = 0; mf < 4; ++mf) {
#pragma unroll
      for (int nf = 0; nf < 4; ++nf) {
        f32x4 a = acc[mf][nf];
        a = __builtin_amdgcn_mfma_f32_16x16x32_bf16(Alf[mf], Bh[nf], a, 0, 0, 0);
        a = __builtin_amdgcn_mfma_f32_16x16x32_bf16(Ahf[mf], Bl[nf], a, 0, 0, 0);
        a = __builtin_amdgcn_mfma_f32_16x16x32_bf16(Ahf[mf], Bh[nf], a, 0, 0, 0);
        acc[mf][nf] = a;
      }
    }
    __syncthreads();
  }

  // ---- epilogue: relu(acc+b2) dot w3, reduce over 16 lanes (g), atomic to out ----
  float b2v[4], w3v[4];
#pragma unroll
  for (int nf = 0; nf < 4; ++nf) {
    int g = bg0 + nf * 16;
    b2v[nf] = b2[g];
    w3v[nf] = w3[g];
  }
  const float b3v = (ntile == 0 && wn == 0) ? b3[0] : 0.f;
#pragma unroll
  for (int mf = 0; mf < 4; ++mf) {
#pragma unroll
    for (int r = 0; r < 4; ++r) {
      float s = 0.f;
#pragma unroll
      for (int nf = 0; nf < 4; ++nf) {
        // C/D layout (measured m89/m91): col = lane&15, row = (lane>>4)*4 + r
        float h2 = fmaxf(acc[mf][nf][r] + b2v[nf], 0.f);
        s = fmaf(w3v[nf], h2, s);
      }
      s += __shfl_xor(s, 1);
      s += __shfl_xor(s, 2);
      s += __shfl_xor(s, 4);
      s += __shfl_xor(s, 8);
      if ((lane & 15) == 0) {
        int p = wm * 64 + mf * 16 + ((lane >> 4) << 2) + r;  // i_l*16 + j_l
        atomicAdd(out + (ibase + (p >> 4)) * B_ + (jbase + (p & 15)), s + b3v);
      }
    }
  }
}

extern "C" void kernel_launch(void* const* d_in, const int* in_sizes, int n_in,
                              void* d_out, int out_size, void* d_ws, size_t ws_size,
                              hipStream_t stream) {
  const float* x  = (const float*)d_in[0];
  const float* y  = (const float*)d_in[1];
  const float* W1 = (const float*)d_in[2];
  const float* b1 = (const float*)d_in[3];
  const float* W2 = (const float*)d_in[4];
  const float* b2 = (const float*)d_in[5];
  const float* W3 = (const float*)d_in[6];
  const float* b3 = (const float*)d_in[7];
  float* out = (float*)d_out;

  char* ws = (char*)d_ws;
  float* hx = (float*)ws;                                   // 1 MB
  float* hy = (float*)(ws + (1u << 20));                    // 1 MB
  unsigned short* w2hi = (unsigned short*)(ws + (2u << 20));            // 512 KB
  unsigned short* w2lo = (unsigned short*)(ws + (2u << 20) + (512u * 1024u));  // 512 KB

  hipMemsetAsync(d_out, 0, (size_t)out_size * sizeof(float), stream);
  k_prep<<<1024, 256, 0, stream>>>(x, y, W1, b1, hx, hy);
  k_split<<<1024, 256, 0, stream>>>(W2, w2hi, w2lo);
  k_main<<<4096, 512, 0, stream>>>(hx, hy, w2hi, w2lo, b2, W3, b3, out);
}

// Round 3
// 572.995 us; speedup vs baseline: 1.5055x; 1.5055x over previous
//
#include <hip/hip_runtime.h>

#define B_ 512
#define H_ 512

typedef __attribute__((ext_vector_type(8))) short short8;
typedef __attribute__((ext_vector_type(4))) float f32x4;

__device__ __forceinline__ unsigned short bf16rne(float f) {
  unsigned u = __float_as_uint(f);
  u += 0x7FFFu + ((u >> 16) & 1u);
  return (unsigned short)(u >> 16);
}

// hx[j][h] = sum_n x[j][n]*W1[h][n] + b1[h]   (b1 folded into hx)
// hy[i][h] = sum_n y[i][n]*W1[h][128+n]
__global__ __launch_bounds__(256) void k_prep(const float* __restrict__ x,
                                              const float* __restrict__ y,
                                              const float* __restrict__ W1,
                                              const float* __restrict__ b1,
                                              float* __restrict__ hx,
                                              float* __restrict__ hy) {
  __shared__ float xs[128];
  const int b = blockIdx.x;          // 0..1023
  const bool isx = b < B_;
  const int row = isx ? b : b - B_;
  const float* src = (isx ? x : y) + row * 128;
  const int t = threadIdx.x;
  if (t < 32) ((float4*)xs)[t] = ((const float4*)src)[t];
  __syncthreads();
  const int woff = isx ? 0 : 128;
  float* dst = (isx ? hx : hy) + row * H_;
  for (int h = t; h < H_; h += 256) {
    const float4* wr = (const float4*)(W1 + h * 256 + woff);
    float acc = isx ? b1[h] : 0.f;
#pragma unroll
    for (int n = 0; n < 32; ++n) {
      float4 w = wr[n];
      float4 xv = ((const float4*)xs)[n];
      acc = fmaf(w.x, xv.x, acc);
      acc = fmaf(w.y, xv.y, acc);
      acc = fmaf(w.z, xv.z, acc);
      acc = fmaf(w.w, xv.w, acc);
    }
    dst[h] = acc;
  }
}

// Split W2 into bf16 hi/lo planes, REPACKED into MFMA B-fragment order:
// dst[d] where d = gt*8192 + c*512 + ks*128 + g15*8 + e
//   g = gt*16 + g15 (output col within frag = lane&15)
//   k = c*32 + ks*8 + e (ks = lane>>4)
// so a wave's 16B/lane frag load at chunk c, g-tile gt is one contiguous 1KB.
__global__ __launch_bounds__(256) void k_split(const float* __restrict__ W2,
                                               unsigned short* __restrict__ hi,
                                               unsigned short* __restrict__ lo) {
  int d = blockIdx.x * 256 + threadIdx.x;  // grid 1024 -> 262144
  int e = d & 7;
  int g15 = (d >> 3) & 15;
  int ks = (d >> 7) & 3;
  int c = (d >> 9) & 15;
  int gt = d >> 13;
  int g = gt * 16 + g15;
  int k = c * 32 + ks * 8 + e;
  float v = W2[g * H_ + k];
  unsigned short h = bf16rne(v);
  hi[d] = h;
  float r = v - __uint_as_float(((unsigned)h) << 16);
  lo[d] = bf16rne(r);
}

// add + relu + truncation hi/lo split of 8 values -> two bf16x8 fragments
__device__ __forceinline__ void build8(const float4& xa, const float4& xb,
                                       const float4& ya, const float4& yb,
                                       short8& Hf, short8& Lf) {
  float v[8] = {xa.x + ya.x, xa.y + ya.y, xa.z + ya.z, xa.w + ya.w,
                xb.x + yb.x, xb.y + yb.y, xb.z + yb.z, xb.w + yb.w};
#pragma unroll
  for (int q = 0; q < 8; ++q) {
    float t = fmaxf(v[q], 0.f);
    unsigned u = __float_as_uint(t);
    Hf[q] = (short)(u >> 16);                       // chop hi (t >= 0)
    float r = t - __uint_as_float(u & 0xFFFF0000u); // exact residual
    Lf[q] = (short)(__float_as_uint(r) >> 16);      // chop lo, err ~2^-17
  }
}

// Fused middle layer, register-built A, no LDS, no barriers.
// Block = 256 thr (4 waves). Block tile: 128 pairs (8 i x 16 j) x 128 g.
// Wave w: pairs [w*32, w*32+32) -> frag mf has uniform i_l = w*2+mf, j_l = lane&15.
// All 4 waves share the g-range -> B frags L1-resident.
__global__ __launch_bounds__(256, 3) void k_main(
    const float* __restrict__ hx, const float* __restrict__ hy,
    const unsigned short* __restrict__ w2hi, const unsigned short* __restrict__ w2lo,
    const float* __restrict__ b2, const float* __restrict__ w3,
    const float* __restrict__ b3, float* __restrict__ out) {
  const int tid = threadIdx.x;
  const int lane = tid & 63;
  const int wid = tid >> 6;   // 0..3

  const int bid = blockIdx.x;
  const int ntile = bid & 3;
  const int mtile = bid >> 2;            // 0..2047
  const int ibase = (mtile >> 5) << 3;   // i tiled by 8
  const int jbase = (mtile & 31) << 4;   // j tiled by 16
  const int l15 = lane & 15;
  const int kslot = (lane >> 4) << 3;    // 0,8,16,24

  const float* hxp = hx + (jbase + l15) * H_ + kslot;
  const float* hyp0 = hy + (ibase + wid * 2 + 0) * H_ + kslot;
  const float* hyp1 = hy + (ibase + wid * 2 + 1) * H_ + kslot;
  // packed B plane base for this block's g-tile (gt0 = ntile*8), this lane
  const unsigned short* pbh = w2hi + (ntile * 8) * 8192 + lane * 8;
  const unsigned short* pbl = w2lo + (ntile * 8) * 8192 + lane * 8;

  f32x4 acc[2][8] = {};

  // stage chunk 0 A-inputs
  float4 xa = *(const float4*)(hxp);
  float4 xb = *(const float4*)(hxp + 4);
  float4 y0a = *(const float4*)(hyp0);
  float4 y0b = *(const float4*)(hyp0 + 4);
  float4 y1a = *(const float4*)(hyp1);
  float4 y1b = *(const float4*)(hyp1 + 4);

#pragma unroll 1
  for (int c = 0; c < 16; ++c) {
    short8 Ah0, Al0, Ah1, Al1;
    build8(xa, xb, y0a, y0b, Ah0, Al0);
    build8(xa, xb, y1a, y1b, Ah1, Al1);
    if (c < 15) {  // issue next-chunk A loads early; fly under the MFMAs
      const int ko = (c + 1) * 32;
      xa = *(const float4*)(hxp + ko);
      xb = *(const float4*)(hxp + ko + 4);
      y0a = *(const float4*)(hyp0 + ko);
      y0b = *(const float4*)(hyp0 + ko + 4);
      y1a = *(const float4*)(hyp1 + ko);
      y1b = *(const float4*)(hyp1 + ko + 4);
    }
    const unsigned short* bh = pbh + c * 512;
    const unsigned short* bl = pbl + c * 512;
#pragma unroll
    for (int nf = 0; nf < 8; ++nf) {
      short8 Bh = *(const short8*)(bh + nf * 8192);
      short8 Bl = *(const short8*)(bl + nf * 8192);
      f32x4 a0 = acc[0][nf];
      a0 = __builtin_amdgcn_mfma_f32_16x16x32_bf16(Al0, Bh, a0, 0, 0, 0);
      a0 = __builtin_amdgcn_mfma_f32_16x16x32_bf16(Ah0, Bl, a0, 0, 0, 0);
      a0 = __builtin_amdgcn_mfma_f32_16x16x32_bf16(Ah0, Bh, a0, 0, 0, 0);
      acc[0][nf] = a0;
      f32x4 a1 = acc[1][nf];
      a1 = __builtin_amdgcn_mfma_f32_16x16x32_bf16(Al1, Bh, a1, 0, 0, 0);
      a1 = __builtin_amdgcn_mfma_f32_16x16x32_bf16(Ah1, Bl, a1, 0, 0, 0);
      a1 = __builtin_amdgcn_mfma_f32_16x16x32_bf16(Ah1, Bh, a1, 0, 0, 0);
      acc[1][nf] = a1;
    }
  }

  // epilogue: relu(acc+b2) dot w3, shfl-reduce over the 16 g-lanes, atomic out
  const int gbase = ntile << 7;
  float b2v[8], w3v[8];
#pragma unroll
  for (int nf = 0; nf < 8; ++nf) {
    int g = gbase + nf * 16 + l15;
    b2v[nf] = b2[g];
    w3v[nf] = w3[g];
  }
  const float b3v = (ntile == 0) ? b3[0] : 0.f;
#pragma unroll
  for (int mf = 0; mf < 2; ++mf) {
#pragma unroll
    for (int r = 0; r < 4; ++r) {
      float s = 0.f;
#pragma unroll
      for (int nf = 0; nf < 8; ++nf) {
        // C/D layout (m89/m91): col = lane&15 (g), row = (lane>>4)*4 + r (j_l)
        float h2 = fmaxf(acc[mf][nf][r] + b2v[nf], 0.f);
        s = fmaf(w3v[nf], h2, s);
      }
      s += __shfl_xor(s, 1);
      s += __shfl_xor(s, 2);
      s += __shfl_xor(s, 4);
      s += __shfl_xor(s, 8);
      if (l15 == 0) {
        int jl = ((lane >> 4) << 2) + r;
        int il = wid * 2 + mf;
        atomicAdd(out + (ibase + il) * B_ + jbase + jl, s + b3v);
      }
    }
  }
}

extern "C" void kernel_launch(void* const* d_in, const int* in_sizes, int n_in,
                              void* d_out, int out_size, void* d_ws, size_t ws_size,
                              hipStream_t stream) {
  const float* x  = (const float*)d_in[0];
  const float* y  = (const float*)d_in[1];
  const float* W1 = (const float*)d_in[2];
  const float* b1 = (const float*)d_in[3];
  const float* W2 = (const float*)d_in[4];
  const float* b2 = (const float*)d_in[5];
  const float* W3 = (const float*)d_in[6];
  const float* b3 = (const float*)d_in[7];
  float* out = (float*)d_out;

  char* ws = (char*)d_ws;
  float* hx = (float*)ws;                                   // 1 MB
  float* hy = (float*)(ws + (1u << 20));                    // 1 MB
  unsigned short* w2hi = (unsigned short*)(ws + (2u << 20));                    // 512 KB
  unsigned short* w2lo = (unsigned short*)(ws + (2u << 20) + (512u * 1024u));   // 512 KB

  hipMemsetAsync(d_out, 0, (size_t)out_size * sizeof(float), stream);
  k_prep<<<1024, 256, 0, stream>>>(x, y, W1, b1, hx, hy);
  k_split<<<1024, 256, 0, stream>>>(W2, w2hi, w2lo);
  k_main<<<8192, 256, 0, stream>>>(hx, hy, w2hi, w2lo, b2, W3, b3, out);
}

// Round 6
// 437.363 us; speedup vs baseline: 1.9724x; 1.3101x over previous
//
#include <hip/hip_runtime.h>

#define B_ 512
#define H_ 512

typedef short short8 __attribute__((ext_vector_type(8)));
typedef float f32x4 __attribute__((ext_vector_type(4)));

__device__ __forceinline__ unsigned short bf16rne(float f) {
  unsigned u = __float_as_uint(f);
  u += 0x7FFFu + ((u >> 16) & 1u);
  return (unsigned short)(u >> 16);
}

// hx[j][h] = sum_n x[j][n]*W1[h][n] + b1[h]   (b1 folded into hx)
// hy[i][h] = sum_n y[i][n]*W1[h][128+n]
__global__ __launch_bounds__(256) void k_prep(const float* __restrict__ x,
                                              const float* __restrict__ y,
                                              const float* __restrict__ W1,
                                              const float* __restrict__ b1,
                                              float* __restrict__ hx,
                                              float* __restrict__ hy) {
  __shared__ float xs[128];
  const int b = blockIdx.x;          // 0..1023
  const bool isx = b < B_;
  const int row = isx ? b : b - B_;
  const float* src = (isx ? x : y) + row * 128;
  const int t = threadIdx.x;
  if (t < 32) ((float4*)xs)[t] = ((const float4*)src)[t];
  __syncthreads();
  const int woff = isx ? 0 : 128;
  float* dst = (isx ? hx : hy) + row * H_;
  for (int h = t; h < H_; h += 256) {
    const float4* wr = (const float4*)(W1 + h * 256 + woff);
    float acc = isx ? b1[h] : 0.f;
#pragma unroll
    for (int n = 0; n < 32; ++n) {
      float4 w = wr[n];
      float4 xv = ((const float4*)xs)[n];
      acc = fmaf(w.x, xv.x, acc);
      acc = fmaf(w.y, xv.y, acc);
      acc = fmaf(w.z, xv.z, acc);
      acc = fmaf(w.w, xv.w, acc);
    }
    dst[h] = acc;
  }
}

// Pack W2 hi/lo bf16 planes into the per-(ntile, chunk) staging stream:
// d = nt*131072 + c*8192 + plane*4096 + nf*512 + ks*128 + g15*8 + e  (shorts)
//   g = nt*128 + nf*16 + g15,  k = c*32 + ks*8 + e
// One chunk = 16 KB contiguous -> 4 global_load_lds dwordx4 issues per wave.
__global__ __launch_bounds__(256) void k_pack(const float* __restrict__ W2,
                                              unsigned short* __restrict__ w2p) {
  int d = blockIdx.x * 256 + threadIdx.x;  // grid 2048 -> 524288
  int e = d & 7;
  int g15 = (d >> 3) & 15;
  int ks = (d >> 7) & 3;
  int nf = (d >> 9) & 7;
  int plane = (d >> 12) & 1;
  int c = (d >> 13) & 15;
  int nt = (d >> 17) & 3;
  int g = nt * 128 + nf * 16 + g15;
  int k = c * 32 + ks * 8 + e;
  float v = W2[g * H_ + k];
  unsigned short h = bf16rne(v);
  float r = v - __uint_as_float(((unsigned)h) << 16);
  w2p[d] = plane ? bf16rne(r) : h;
}

// add + relu + exact truncation hi/lo split, packed 2-at-a-time via v_perm
__device__ __forceinline__ void build8(const float4& xa, const float4& xb,
                                       const float4& ya, const float4& yb,
                                       short8& Hf, short8& Lf) {
  float v[8] = {xa.x + ya.x, xa.y + ya.y, xa.z + ya.z, xa.w + ya.w,
                xb.x + yb.x, xb.y + yb.y, xb.z + yb.z, xb.w + yb.w};
  union { unsigned u[4]; short8 s; } H, L;
#pragma unroll
  for (int p = 0; p < 4; ++p) {
    float t0 = fmaxf(v[2 * p], 0.f);
    float t1 = fmaxf(v[2 * p + 1], 0.f);
    unsigned u0 = __float_as_uint(t0);
    unsigned u1 = __float_as_uint(t1);
    // D = {u0.b2,u0.b3,u1.b2,u1.b3}: elem0 hi16 in low short
    H.u[p] = __builtin_amdgcn_perm(u1, u0, 0x07060302);
    float r0 = t0 - __uint_as_float(u0 & 0xFFFF0000u);  // exact residual
    float r1 = t1 - __uint_as_float(u1 & 0xFFFF0000u);
    L.u[p] = __builtin_amdgcn_perm(__float_as_uint(r1), __float_as_uint(r0),
                                   0x07060302);
  }
  Hf = H.s;
  Lf = L.s;
}

// Fused middle layer: register-built A + LDS-staged B (double-buffered).
// Block = 256 thr (4 waves). Block tile: 128 pairs (8 i x 16 j) x 128 g.
// B staged once per block per chunk via global_load_lds; barrier at chunk end
// sits ~900cy after the stage issue -> latency hidden despite vmcnt(0) drain.
__global__ __launch_bounds__(256, 4) void k_main(
    const float* __restrict__ hx, const float* __restrict__ hy,
    const unsigned short* __restrict__ w2p,
    const float* __restrict__ b2, const float* __restrict__ w3,
    const float* __restrict__ b3, float* __restrict__ out) {
  __shared__ alignas(16) unsigned short Bs[2][8192];  // 2 x 16 KB

  const int tid = threadIdx.x;
  const int lane = tid & 63;
  const int wid = tid >> 6;   // 0..3

  const int bid = blockIdx.x;
  const int ntile = bid & 3;
  const int mtile = bid >> 2;            // 0..2047
  const int ibase = (mtile >> 5) << 3;   // i tiled by 8
  const int jbase = (mtile & 31) << 4;   // j tiled by 16
  const int l15 = lane & 15;
  const int kslot = (lane >> 4) << 3;    // 0,8,16,24

  const float* hxp = hx + (jbase + l15) * H_ + kslot;
  const float* hyp0 = hy + (ibase + wid * 2 + 0) * H_ + kslot;
  const float* hyp1 = hy + (ibase + wid * 2 + 1) * H_ + kslot;

  // per-lane global source for staging (wave w stages 4 KB of the 16 KB chunk)
  const unsigned short* gstage = w2p + ntile * 131072 + wid * 2048 + lane * 8;

  auto STAGE = [&](int c, int buf) {
    const unsigned short* g = gstage + c * 8192;
    unsigned short* l = &Bs[buf][wid * 2048];
#pragma unroll
    for (int q = 0; q < 4; ++q) {
      __builtin_amdgcn_global_load_lds(
          (const __attribute__((address_space(1))) unsigned int*)(g + q * 512),
          (__attribute__((address_space(3))) unsigned int*)(l + q * 512),
          16, 0, 0);
    }
  };

  f32x4 acc[2][8] = {};

  STAGE(0, 0);
  // stage chunk-0 A inputs
  float4 xa = *(const float4*)(hxp);
  float4 xb = *(const float4*)(hxp + 4);
  float4 y0a = *(const float4*)(hyp0);
  float4 y0b = *(const float4*)(hyp0 + 4);
  float4 y1a = *(const float4*)(hyp1);
  float4 y1b = *(const float4*)(hyp1 + 4);
  __syncthreads();  // vmcnt(0) drain: chunk-0 stage + A loads complete

#pragma unroll 2
  for (int c = 0; c < 16; ++c) {
    const int buf = c & 1;
    if (c < 15) STAGE(c + 1, buf ^ 1);  // issue early; hides under MFMAs
    short8 Ah0, Al0, Ah1, Al1;
    build8(xa, xb, y0a, y0b, Ah0, Al0);
    build8(xa, xb, y1a, y1b, Ah1, Al1);
    if (c < 15) {  // prefetch next-chunk A inputs
      const int ko = (c + 1) * 32;
      xa = *(const float4*)(hxp + ko);
      xb = *(const float4*)(hxp + ko + 4);
      y0a = *(const float4*)(hyp0 + ko);
      y0b = *(const float4*)(hyp0 + ko + 4);
      y1a = *(const float4*)(hyp1 + ko);
      y1b = *(const float4*)(hyp1 + ko + 4);
    }
    const unsigned short* bb = &Bs[buf][0] + lane * 8;
#pragma unroll
    for (int nf = 0; nf < 8; ++nf) {
      short8 Bh = *(const short8*)(bb + nf * 512);
      short8 Bl = *(const short8*)(bb + 4096 + nf * 512);
      f32x4 a0 = acc[0][nf];
      a0 = __builtin_amdgcn_mfma_f32_16x16x32_bf16(Al0, Bh, a0, 0, 0, 0);
      a0 = __builtin_amdgcn_mfma_f32_16x16x32_bf16(Ah0, Bl, a0, 0, 0, 0);
      a0 = __builtin_amdgcn_mfma_f32_16x16x32_bf16(Ah0, Bh, a0, 0, 0, 0);
      acc[0][nf] = a0;
      f32x4 a1 = acc[1][nf];
      a1 = __builtin_amdgcn_mfma_f32_16x16x32_bf16(Al1, Bh, a1, 0, 0, 0);
      a1 = __builtin_amdgcn_mfma_f32_16x16x32_bf16(Ah1, Bl, a1, 0, 0, 0);
      a1 = __builtin_amdgcn_mfma_f32_16x16x32_bf16(Ah1, Bh, a1, 0, 0, 0);
      acc[1][nf] = a1;
    }
    __syncthreads();  // stage(c+1) done; all waves finished reading buf
  }

  // epilogue: relu(acc+b2) dot w3, shfl-reduce over the 16 g-lanes, atomic out
  const int gbase = ntile << 7;
  float b2v[8], w3v[8];
#pragma unroll
  for (int nf = 0; nf < 8; ++nf) {
    int g = gbase + nf * 16 + l15;
    b2v[nf] = b2[g];
    w3v[nf] = w3[g];
  }
  const float b3v = (ntile == 0) ? b3[0] : 0.f;
#pragma unroll
  for (int mf = 0; mf < 2; ++mf) {
#pragma unroll
    for (int r = 0; r < 4; ++r) {
      float s = 0.f;
#pragma unroll
      for (int nf = 0; nf < 8; ++nf) {
        // C/D layout (m89/m91): col = lane&15 (g), row = (lane>>4)*4 + r (j_l)
        float h2 = fmaxf(acc[mf][nf][r] + b2v[nf], 0.f);
        s = fmaf(w3v[nf], h2, s);
      }
      s += __shfl_xor(s, 1);
      s += __shfl_xor(s, 2);
      s += __shfl_xor(s, 4);
      s += __shfl_xor(s, 8);
      if (l15 == 0) {
        int jl = ((lane >> 4) << 2) + r;
        int il = wid * 2 + mf;
        atomicAdd(out + (ibase + il) * B_ + jbase + jl, s + b3v);
      }
    }
  }
}

extern "C" void kernel_launch(void* const* d_in, const int* in_sizes, int n_in,
                              void* d_out, int out_size, void* d_ws, size_t ws_size,
                              hipStream_t stream) {
  const float* x  = (const float*)d_in[0];
  const float* y  = (const float*)d_in[1];
  const float* W1 = (const float*)d_in[2];
  const float* b1 = (const float*)d_in[3];
  const float* W2 = (const float*)d_in[4];
  const float* b2 = (const float*)d_in[5];
  const float* W3 = (const float*)d_in[6];
  const float* b3 = (const float*)d_in[7];
  float* out = (float*)d_out;

  char* ws = (char*)d_ws;
  float* hx = (float*)ws;                                   // 1 MB
  float* hy = (float*)(ws + (1u << 20));                    // 1 MB
  unsigned short* w2p = (unsigned short*)(ws + (2u << 20)); // 1 MB packed hi/lo

  hipMemsetAsync(d_out, 0, (size_t)out_size * sizeof(float), stream);
  k_prep<<<1024, 256, 0, stream>>>(x, y, W1, b1, hx, hy);
  k_pack<<<2048, 256, 0, stream>>>(W2, w2p);
  k_main<<<8192, 256, 0, stream>>>(hx, hy, w2p, b2, W3, b3, out);
}